// Round 1
// baseline (598.442 us; speedup 1.0000x reference)
//
#include <hip/hip_runtime.h>
#include <hip/hip_bf16.h>
#include <math.h>

#define BATCH 64
#define TLEN 512
#define DIM 768
#define NLAB 50

#define NEGINF (-__builtin_inff())

// ---------------------------------------------------------------------------
// GEMM: logits[B*T][L] = emb[B*T][D] @ W[D][L] + bias
// TM=64 rows/block, block=128 threads (tx 0..7 x ty 0..15), thread tile 4x8,
// BK=32. A tile in LDS stride 33 (bank-spread), W tile stride 64.
// ---------------------------------------------------------------------------
#define TM 64
#define BK 32
#define LDA 33

__global__ __launch_bounds__(128) void gemm_kernel(
    const float* __restrict__ A,     // [B*T, D]
    const float* __restrict__ W,     // [D, L]
    const float* __restrict__ bias,  // [L]
    float* __restrict__ out)         // [B*T, L]
{
    __shared__ float As[TM * LDA];
    __shared__ float Ws[BK * 64];

    const int tid = threadIdx.x;
    const int tx = tid & 7;     // col group (8 cols each)
    const int ty = tid >> 3;    // row group (4 rows each), 0..15
    const int r0 = blockIdx.x * TM;

    float acc[4][8];
#pragma unroll
    for (int i = 0; i < 4; ++i)
#pragma unroll
        for (int j = 0; j < 8; ++j) acc[i][j] = 0.f;

    for (int k0 = 0; k0 < DIM; k0 += BK) {
        // stage A: 64 rows x 32 k = 512 float4, 4 per thread
#pragma unroll
        for (int it = 0; it < 4; ++it) {
            int u = tid + it * 128;       // float4 index
            int row = u >> 3;             // 8 float4 per row
            int kq = u & 7;
            const float4 v = ((const float4*)(A + (size_t)(r0 + row) * DIM + k0))[kq];
            float* dst = &As[row * LDA + kq * 4];
            dst[0] = v.x; dst[1] = v.y; dst[2] = v.z; dst[3] = v.w;
        }
        // stage W: 32 k x 64 cols (cols >= 50 zero), 16 scalars per thread
#pragma unroll
        for (int it = 0; it < 16; ++it) {
            int u = tid + it * 128;
            int kk = u >> 6;
            int c = u & 63;
            Ws[u] = (c < NLAB) ? W[(k0 + kk) * NLAB + c] : 0.f;
        }
        __syncthreads();

#pragma unroll
        for (int kk = 0; kk < BK; ++kk) {
            float a0 = As[(ty * 4 + 0) * LDA + kk];
            float a1 = As[(ty * 4 + 1) * LDA + kk];
            float a2 = As[(ty * 4 + 2) * LDA + kk];
            float a3 = As[(ty * 4 + 3) * LDA + kk];
            const float4 w0 = *(const float4*)&Ws[kk * 64 + tx * 8];
            const float4 w1 = *(const float4*)&Ws[kk * 64 + tx * 8 + 4];
            const float wv[8] = {w0.x, w0.y, w0.z, w0.w, w1.x, w1.y, w1.z, w1.w};
#pragma unroll
            for (int j = 0; j < 8; ++j) {
                acc[0][j] = fmaf(a0, wv[j], acc[0][j]);
                acc[1][j] = fmaf(a1, wv[j], acc[1][j]);
                acc[2][j] = fmaf(a2, wv[j], acc[2][j]);
                acc[3][j] = fmaf(a3, wv[j], acc[3][j]);
            }
        }
        __syncthreads();
    }

    // epilogue: add bias, scalar stores (out may be 4B-aligned only)
#pragma unroll
    for (int j = 0; j < 8; ++j) {
        int col = tx * 8 + j;
        if (col < NLAB) {
            float bv = bias[col];
#pragma unroll
            for (int i = 0; i < 4; ++i) {
                out[(size_t)(r0 + ty * 4 + i) * NLAB + col] = acc[i][j] + bv;
            }
        }
    }
}

// ---------------------------------------------------------------------------
// CRF: one wave (64 threads) per batch. Lane j owns label j (j<50).
// alpha'_j = M + log( sum_i exp(alpha_i - M) * expT[i][j] ) + em_j
// expT precomputed in registers (constant over time).
// ---------------------------------------------------------------------------
__device__ __forceinline__ float wave_max(float v) {
#pragma unroll
    for (int off = 32; off > 0; off >>= 1) v = fmaxf(v, __shfl_xor(v, off, 64));
    return v;
}
__device__ __forceinline__ float wave_sum(float v) {
#pragma unroll
    for (int off = 32; off > 0; off >>= 1) v += __shfl_xor(v, off, 64);
    return v;
}

__global__ __launch_bounds__(64) void crf_kernel(
    const float* __restrict__ logits,  // [B*T*L]
    const int* __restrict__ labels,    // [B*T]
    const void* __restrict__ maskp,    // [B*T] unknown repr (int32/byte/f32/bf16)
    const float* __restrict__ startT,  // [L]
    const float* __restrict__ endT,    // [L]
    const float* __restrict__ trans,   // [L*L]
    float* __restrict__ llh)           // [B]
{
    const int b = blockIdx.x;
    const int lane = threadIdx.x;
    __shared__ float ea[64];

    // --- determine mask representation + compute length (contiguous prefix) ---
    const int probe = ((const int*)maskp)[0];  // mask[0,0..]=1 always
    int len = 0;
    if (probe == 1) {  // int32 elements
        const int* m = (const int*)maskp + b * TLEN;
#pragma unroll
        for (int it = 0; it < 8; ++it)
            len += (int)__popcll(__ballot(m[lane + it * 64] != 0));
    } else if (probe == 0x01010101) {  // 1-byte bool elements
        const unsigned char* m = (const unsigned char*)maskp + b * TLEN;
#pragma unroll
        for (int it = 0; it < 8; ++it)
            len += (int)__popcll(__ballot(m[lane + it * 64] != 0));
    } else if (probe == 0x3F803F80) {  // bf16 elements
        const unsigned short* m = (const unsigned short*)maskp + b * TLEN;
#pragma unroll
        for (int it = 0; it < 8; ++it)
            len += (int)__popcll(__ballot(m[lane + it * 64] != 0));
    } else {  // float32 elements
        const float* m = (const float*)maskp + b * TLEN;
#pragma unroll
        for (int it = 0; it < 8; ++it)
            len += (int)__popcll(__ballot(m[lane + it * 64] != 0.f));
    }

    const int j = lane;

    // --- precompute expT[i] = exp(trans[i][j]) into registers ---
    float et[52];
#pragma unroll
    for (int i = 0; i < 52; ++i) et[i] = 0.f;
    if (j < NLAB) {
#pragma unroll
        for (int i = 0; i < NLAB; ++i) et[i] = __expf(trans[i * NLAB + j]);
    }

    const float* em = logits + (size_t)b * TLEN * NLAB;

    float alpha = NEGINF;
    if (j < NLAB) alpha = startT[j] + em[j];

    // --- forward recurrence (denominator) ---
    for (int t = 1; t < len; ++t) {
        const float emv = (j < NLAB) ? em[t * NLAB + j] : 0.f;  // prefetch
        const float M = wave_max(alpha);
        const float e = __expf(alpha - M);  // lanes >= 50: exp(-inf)=0
        ea[lane] = e;
        __syncthreads();
        float s = 0.f;
#pragma unroll
        for (int i4 = 0; i4 < 13; ++i4) {
            const float4 v = *(const float4*)&ea[i4 * 4];
            s = fmaf(v.x, et[i4 * 4 + 0], s);
            s = fmaf(v.y, et[i4 * 4 + 1], s);
            s = fmaf(v.z, et[i4 * 4 + 2], s);
            s = fmaf(v.w, et[i4 * 4 + 3], s);
        }
        __syncthreads();
        alpha = (j < NLAB) ? (M + __logf(s) + emv) : NEGINF;
    }

    // --- denominator: logsumexp(alpha + end) ---
    const float v = (j < NLAB) ? (alpha + endT[j]) : NEGINF;
    const float M2 = wave_max(v);
    const float s2 = wave_sum(__expf(v - M2));
    const float den = M2 + __logf(s2);

    // --- numerator: gold path score (mask is contiguous -> fully parallel) ---
    const int* tg = labels + b * TLEN;
    float num = 0.f;
#pragma unroll
    for (int it = 0; it < 8; ++it) {
        const int t = lane + it * 64;
        if (t < len) {
            const int tag = tg[t];
            num += em[t * NLAB + tag];
            if (t >= 1) num += trans[tg[t - 1] * NLAB + tag];
        }
    }
    num = wave_sum(num);
    if (lane == 0) {
        num += startT[tg[0]] + endT[tg[len - 1]];
        llh[b] = num - den;
    }
}

// ---------------------------------------------------------------------------
// final: out[0] = -mean(llh)
// ---------------------------------------------------------------------------
__global__ __launch_bounds__(64) void loss_kernel(const float* __restrict__ llh,
                                                  float* __restrict__ out0) {
    float v = llh[threadIdx.x];
    v = wave_sum(v);
    if (threadIdx.x == 0) out0[0] = -(v * (1.0f / BATCH));
}

extern "C" void kernel_launch(void* const* d_in, const int* in_sizes, int n_in,
                              void* d_out, int out_size, void* d_ws, size_t ws_size,
                              hipStream_t stream) {
    (void)in_sizes; (void)n_in; (void)out_size; (void)ws_size;
    const float* emb    = (const float*)d_in[0];
    const int*   labels = (const int*)d_in[1];
    const void*  mask   = d_in[2];
    const float* W      = (const float*)d_in[3];
    const float* bias   = (const float*)d_in[4];
    const float* startT = (const float*)d_in[5];
    const float* endT   = (const float*)d_in[6];
    const float* trans  = (const float*)d_in[7];

    float* out    = (float*)d_out;
    float* logits = out + 1;          // outputs: [-loss (1)] ++ [logits (B*T*L)]
    float* llh    = (float*)d_ws;     // 64 floats scratch

    gemm_kernel<<<(BATCH * TLEN) / TM, 128, 0, stream>>>(emb, W, bias, logits);
    crf_kernel<<<BATCH, 64, 0, stream>>>(logits, labels, mask, startT, endT, trans, llh);
    loss_kernel<<<1, 64, 0, stream>>>(llh, out);
}

// Round 2
// 347.708 us; speedup vs baseline: 1.7211x; 1.7211x over previous
//
#include <hip/hip_runtime.h>
#include <hip/hip_bf16.h>
#include <math.h>

#define BATCH 64
#define TLEN 512
#define DIM 768
#define NLAB 50

#define NEGINF (-__builtin_inff())

typedef __attribute__((ext_vector_type(8))) short short8;   // 8 bf16 (4 VGPRs)
typedef __attribute__((ext_vector_type(4))) float f32x4;    // MFMA acc

__device__ __forceinline__ unsigned short f2bf(float f) {
    // round-to-nearest-even fp32 -> bf16 (inputs are finite, no NaN handling)
    unsigned int u = __float_as_uint(f);
    return (unsigned short)((u + 0x7FFFu + ((u >> 16) & 1u)) >> 16);
}

// ---------------------------------------------------------------------------
// prep: W fp32 [768 x 50]  ->  Bt bf16 [64 cols][768 k] (transposed, zero-pad)
// ---------------------------------------------------------------------------
__global__ __launch_bounds__(256) void wprep_kernel(const float* __restrict__ W,
                                                    unsigned short* __restrict__ Bt) {
    int idx = blockIdx.x * 256 + threadIdx.x;   // 64*768 = 49152
    if (idx < 64 * DIM) {
        int c = idx / DIM;
        int k = idx - c * DIM;
        float v = (c < NLAB) ? W[k * NLAB + c] : 0.f;
        Bt[idx] = f2bf(v);
    }
}

// ---------------------------------------------------------------------------
// GEMM via MFMA bf16: logits[32768 x 50] = A[32768 x 768] @ W + b
// Each wave: 16 rows x 64 cols (4 n-tiles of 16), K-loop in chunks of 32.
// A-frag layout (16x16x32): lane l holds A[m = l&15][k = (l>>4)*8 + j]
// B-frag layout:            lane l holds B[k = (l>>4)*8 + j][n = l&15]
// C/D layout:               col = lane&15, row = (lane>>4)*4 + reg
// ---------------------------------------------------------------------------
__global__ __launch_bounds__(256) void gemm_kernel(const float* __restrict__ A,
                                                   const unsigned short* __restrict__ Bt,
                                                   const float* __restrict__ bias,
                                                   float* __restrict__ out) {
    const int wave = threadIdx.x >> 6;
    const int lane = threadIdx.x & 63;
    const int m = lane & 15;
    const int quad = lane >> 4;
    const int row0 = blockIdx.x * 64 + wave * 16;

    f32x4 acc0 = {0.f, 0.f, 0.f, 0.f};
    f32x4 acc1 = {0.f, 0.f, 0.f, 0.f};
    f32x4 acc2 = {0.f, 0.f, 0.f, 0.f};
    f32x4 acc3 = {0.f, 0.f, 0.f, 0.f};

    const float* arow = A + (size_t)(row0 + m) * DIM + quad * 8;
    const unsigned short* b0 = Bt + (size_t)(0 * 16 + m) * DIM + quad * 8;
    const unsigned short* b1 = Bt + (size_t)(1 * 16 + m) * DIM + quad * 8;
    const unsigned short* b2 = Bt + (size_t)(2 * 16 + m) * DIM + quad * 8;
    const unsigned short* b3 = Bt + (size_t)(3 * 16 + m) * DIM + quad * 8;

#pragma unroll 4
    for (int k0 = 0; k0 < DIM; k0 += 32) {
        const float4 x = *(const float4*)(arow + k0);
        const float4 y = *(const float4*)(arow + k0 + 4);
        short8 af;
        af[0] = (short)f2bf(x.x); af[1] = (short)f2bf(x.y);
        af[2] = (short)f2bf(x.z); af[3] = (short)f2bf(x.w);
        af[4] = (short)f2bf(y.x); af[5] = (short)f2bf(y.y);
        af[6] = (short)f2bf(y.z); af[7] = (short)f2bf(y.w);

        const short8 bf0 = *(const short8*)(b0 + k0);
        const short8 bf1 = *(const short8*)(b1 + k0);
        const short8 bf2 = *(const short8*)(b2 + k0);
        const short8 bf3 = *(const short8*)(b3 + k0);

        acc0 = __builtin_amdgcn_mfma_f32_16x16x32_bf16(af, bf0, acc0, 0, 0, 0);
        acc1 = __builtin_amdgcn_mfma_f32_16x16x32_bf16(af, bf1, acc1, 0, 0, 0);
        acc2 = __builtin_amdgcn_mfma_f32_16x16x32_bf16(af, bf2, acc2, 0, 0, 0);
        acc3 = __builtin_amdgcn_mfma_f32_16x16x32_bf16(af, bf3, acc3, 0, 0, 0);
    }

    // epilogue: D row = quad*4 + r, col = nt*16 + m  (scalar stores, out is 4B-aligned)
    const f32x4 av[4] = {acc0, acc1, acc2, acc3};
#pragma unroll
    for (int nt = 0; nt < 4; ++nt) {
        const int col = nt * 16 + m;
        if (col < NLAB) {
            const float bv = bias[col];
#pragma unroll
            for (int r = 0; r < 4; ++r) {
                const int row = row0 + quad * 4 + r;
                out[(size_t)row * NLAB + col] = av[nt][r] + bv;
            }
        }
    }
}

// ---------------------------------------------------------------------------
// CRF: one wave per batch. Lane j owns label j.
// Representation: e_j = exp(alpha_j - A). Per step:
//   s_j = sum_i e_i * exp(trans[i][j])          (LDS broadcast dot)
//   u_j = s_j * exp(em_j) * rcp(e_0)            (lag-one renormalization)
//   A  += log(e_0)                              (off critical path)
// No wave_max / exp / log in the critical chain.
// ---------------------------------------------------------------------------
__device__ __forceinline__ float wave_sum(float v) {
#pragma unroll
    for (int off = 32; off > 0; off >>= 1) v += __shfl_xor(v, off, 64);
    return v;
}

__global__ __launch_bounds__(64) void crf_kernel(
    const float* __restrict__ logits,  // [B*T*L]
    const int* __restrict__ labels,    // [B*T]
    const void* __restrict__ maskp,    // [B*T] unknown repr
    const float* __restrict__ startT,
    const float* __restrict__ endT,
    const float* __restrict__ trans,
    float* __restrict__ llh) {
    const int b = blockIdx.x;
    const int lane = threadIdx.x;
    __shared__ __align__(16) float ea[64];

    // --- mask length (contiguous valid prefix) ---
    const int probe = ((const int*)maskp)[0];
    int len = 0;
    if (probe == 1) {
        const int* mk = (const int*)maskp + b * TLEN;
#pragma unroll
        for (int it = 0; it < 8; ++it)
            len += (int)__popcll(__ballot(mk[lane + it * 64] != 0));
    } else if (probe == 0x01010101) {
        const unsigned char* mk = (const unsigned char*)maskp + b * TLEN;
#pragma unroll
        for (int it = 0; it < 8; ++it)
            len += (int)__popcll(__ballot(mk[lane + it * 64] != 0));
    } else if (probe == 0x3F803F80) {
        const unsigned short* mk = (const unsigned short*)maskp + b * TLEN;
#pragma unroll
        for (int it = 0; it < 8; ++it)
            len += (int)__popcll(__ballot(mk[lane + it * 64] != 0));
    } else {
        const float* mk = (const float*)maskp + b * TLEN;
#pragma unroll
        for (int it = 0; it < 8; ++it)
            len += (int)__popcll(__ballot(mk[lane + it * 64] != 0.f));
    }

    const int j = lane;
    const int jc = (j < NLAB) ? j : (NLAB - 1);  // clamped for em loads

    // et[i] = exp(trans[i][j]); zero for lanes >= 50 (=> s == 0 there)
    float et[52];
#pragma unroll
    for (int i = 0; i < 52; ++i) et[i] = 0.f;
    if (j < NLAB) {
        for (int i = 0; i < NLAB; ++i) et[i] = __expf(trans[i * NLAB + j]);
    }

    const float* em = logits + (size_t)b * TLEN * NLAB;

    // init: alpha0 = start + em0 ; A = alpha0[0] ; e = exp(alpha0 - A)
    float a0 = (j < NLAB) ? (startT[j] + em[j]) : 0.f;
    const float Abc = __shfl(a0, 0, 64);
    float e = (j < NLAB) ? __expf(a0 - Abc) : 0.f;
    float A = Abc;

    ea[lane] = e;
    __syncthreads();

    float emv = em[1 * NLAB + jc];  // emission for t=1 (len >= 256 always)

    for (int t = 1; t < len; ++t) {
        const int tn = (t + 1 < len) ? (t + 1) : (len - 1);
        const float em_next = em[tn * NLAB + jc];   // prefetch next emission
        const float p = __expf(emv);                 // off critical path

        const float ea0 = ea[0];                     // normalizer (broadcast read)
        float sa = 0.f, sb = 0.f, sc = 0.f, sd = 0.f;
#pragma unroll
        for (int q = 0; q < 13; ++q) {
            const float4 v = *(const float4*)&ea[q * 4];
            sa = fmaf(v.x, et[q * 4 + 0], sa);
            sb = fmaf(v.y, et[q * 4 + 1], sb);
            sc = fmaf(v.z, et[q * 4 + 2], sc);
            sd = fmaf(v.w, et[q * 4 + 3], sd);
        }
        const float s = (sa + sb) + (sc + sd);
        const float r = __builtin_amdgcn_rcpf(ea0);
        const float u = s * (p * r);                 // e' (lanes>=50: s==0 -> u==0)
        A += __logf(ea0);                            // off critical path

        __syncthreads();                             // reads done before overwrite
        ea[lane] = u;
        __syncthreads();                             // write visible before next reads
        e = u;
        emv = em_next;
    }

    // den = A + log( sum_j e_j * exp(end_j) )
    const float wv = (j < NLAB) ? (e * __expf(endT[j])) : 0.f;
    const float den = A + __logf(wave_sum(wv));

    // numerator: gold path score (contiguous mask -> fully parallel)
    const int* tg = labels + b * TLEN;
    float num = 0.f;
#pragma unroll
    for (int it = 0; it < 8; ++it) {
        const int t = lane + it * 64;
        if (t < len) {
            const int tag = tg[t];
            num += em[t * NLAB + tag];
            if (t >= 1) num += trans[tg[t - 1] * NLAB + tag];
        }
    }
    num = wave_sum(num);
    if (lane == 0) {
        num += startT[tg[0]] + endT[tg[len - 1]];
        llh[b] = num - den;
    }
}

__global__ __launch_bounds__(64) void loss_kernel(const float* __restrict__ llh,
                                                  float* __restrict__ out0) {
    float v = llh[threadIdx.x];
    v = wave_sum(v);
    if (threadIdx.x == 0) out0[0] = -(v * (1.0f / BATCH));
}

extern "C" void kernel_launch(void* const* d_in, const int* in_sizes, int n_in,
                              void* d_out, int out_size, void* d_ws, size_t ws_size,
                              hipStream_t stream) {
    (void)in_sizes; (void)n_in; (void)out_size;
    const float* emb    = (const float*)d_in[0];
    const int*   labels = (const int*)d_in[1];
    const void*  mask   = d_in[2];
    const float* W      = (const float*)d_in[3];
    const float* bias   = (const float*)d_in[4];
    const float* startT = (const float*)d_in[5];
    const float* endT   = (const float*)d_in[6];
    const float* trans  = (const float*)d_in[7];

    float* out    = (float*)d_out;
    float* logits = out + 1;                         // outputs: [-loss] ++ logits flat
    float* llh    = (float*)d_ws;                    // 64 floats
    unsigned short* Bt = (unsigned short*)((char*)d_ws + 512);  // 96 KiB bf16 W^T
    (void)ws_size;

    wprep_kernel<<<(64 * DIM + 255) / 256, 256, 0, stream>>>(W, Bt);
    gemm_kernel<<<(BATCH * TLEN) / 64, 256, 0, stream>>>(emb, Bt, bias, logits);
    crf_kernel<<<BATCH, 64, 0, stream>>>(logits, labels, mask, startT, endT, trans, llh);
    loss_kernel<<<1, 64, 0, stream>>>(llh, out);
}